// Round 11
// baseline (346.847 us; speedup 1.0000x reference)
//
#include <hip/hip_runtime.h>

// ---------------------------------------------------------------------------
// EfficientMultiHeadAttention (L=8192,B=2,E=1024,H=16,ws=256,D=64)
// cvt weights -> 3x [cvt activation (roofline) -> fp16 proj GEMM 8-phase] ->
// vtrans -> window attention (barrier-free, K/V from L2) -> output GEMM.
// All GEMMs: 256x256 8-phase counted-vmcnt template (BK=64, K-split halves,
// XOR-swizzled LDS, setprio), A+B via global_load_lds.
// Q projection pre-scaled by 0.125*log2e -> attn softmax uses raw v_exp_f32,
// tree reduces, and defers 1/sum to the output (shfl per q-row).
// Attn: 256-thr blocks (4 waves = 128 q-rows), K/V fragments read per-lane
// from global (L2-hot, no cross-block reuse -> no LDS staging), LDS = 16KB
// per-wave P-bounce only, zero barriers.
// ws (72 MB): W16[8] | X16/Vt[32] | Vp/Ybuf[32]; Qp,Kp parked in d_out.
// ---------------------------------------------------------------------------

typedef _Float16 half8 __attribute__((ext_vector_type(8)));
typedef _Float16 half4 __attribute__((ext_vector_type(4)));
typedef float    f32x4 __attribute__((ext_vector_type(4)));

#define MFMA16(a, b, c) __builtin_amdgcn_mfma_f32_16x16x32_f16((a), (b), (c), 0, 0, 0)
#define VM(n) asm volatile("s_waitcnt vmcnt(" #n ")" ::: "memory")
#define SCHED0 __builtin_amdgcn_sched_barrier(0)
#define LGKM0 do { asm volatile("s_waitcnt lgkmcnt(0)" ::: "memory"); SCHED0; } while (0)
#define BARW do { __builtin_amdgcn_s_barrier(); SCHED0; } while (0)

__device__ inline void gload16(const _Float16* g, _Float16* l) {
  __builtin_amdgcn_global_load_lds(
      (const __attribute__((address_space(1))) void*)g,
      (__attribute__((address_space(3))) void*)l, 16, 0, 0);
}

__device__ inline half8 cvt8(float4 a, float4 b) {
  half8 h = {(_Float16)a.x, (_Float16)a.y, (_Float16)a.z, (_Float16)a.w,
             (_Float16)b.x, (_Float16)b.y, (_Float16)b.z, (_Float16)b.w};
  return h;
}

// ---------------- fp32 -> fp16 convert ----------------
__global__ __launch_bounds__(256) void cvt_fp16_k(const float* __restrict__ src,
                                                  _Float16* __restrict__ dst, int n) {
  int i = (blockIdx.x * 256 + threadIdx.x) * 8;
  if (i >= n) return;
  float4 a = *(const float4*)(src + i);
  float4 b = *(const float4*)(src + i + 4);
  *(half8*)(dst + i) = cvt8(a, b);
}

// weights: 4 matrices in one launch
__global__ __launch_bounds__(256) void cvtw_k(const float* __restrict__ s0,
                                              const float* __restrict__ s1,
                                              const float* __restrict__ s2,
                                              const float* __restrict__ s3,
                                              _Float16* __restrict__ d) {
  const float* s = blockIdx.y == 0 ? s0 : blockIdx.y == 1 ? s1 : blockIdx.y == 2 ? s2 : s3;
  _Float16* dst = d + (size_t)blockIdx.y * (1 << 20);
  int i = (blockIdx.x * 256 + threadIdx.x) * 8;
  float4 a = *(const float4*)(s + i);
  float4 b = *(const float4*)(s + i + 4);
  *(half8*)(dst + i) = cvt8(a, b);
}

// ---------------- 256x256 8-phase fp16 GEMM ----------------
// C[m,n] = (sum_k A[m,k]*W[n,k] + bias[n]) * scale; M=16384, N=K=1024, BK=64.
// [round-7 schedule, measured good; do not re-derive]
template <int OUT_F32>
__global__ __launch_bounds__(512) void gemm8p_k(const _Float16* __restrict__ Ah,
                                                const _Float16* __restrict__ Bw,
                                                const float* __restrict__ bias,
                                                void* __restrict__ Cout, float scale) {
  constexpr int K = 1024, NN = 1024, NT = 16;
  __shared__ alignas(16) _Float16 SH[65536];  // A:[0,32768) B:[32768,65536)
  const int tid = threadIdx.x, lane = tid & 63, wave = tid >> 6;
  const int r15 = lane & 15, g = lane >> 4;
  const int wr = wave >> 2, wc = wave & 3;
  const int m0 = blockIdx.x * 256, n0 = blockIdx.y * 256;

  const int sp = tid >> 3;
  const int sv = (tid & 7) ^ (sp & 7);
  const int srow = 2 * sp + (sv >> 2);
  const int scol = (sv & 3) * 8;
  const int sdst = tid * 8;

  const int rp = r15 >> 1, rsub = r15 & 1;
  const int rslot = ((rsub * 4 + g) ^ rp) * 8;

  f32x4 acc[8][4] = {};
  half8 af[4], bf[4];

#define A_REGION(buf, kh) (&SH[(buf)*16384 + (kh)*8192])
#define B_REGION(buf, kh) (&SH[32768 + (buf)*16384 + (kh)*8192])

#define STAGE_B(t, buf, kh)                                                    \
  do {                                                                         \
    const _Float16* _s = Bw + (size_t)(n0 + srow) * K + (t)*64 + (kh)*32 + scol; \
    gload16(_s, B_REGION(buf, kh) + sdst);                                     \
    gload16(_s + (size_t)128 * K, B_REGION(buf, kh) + sdst + 4096);            \
  } while (0)

#define STAGE_A16(t, buf, kh)                                                  \
  do {                                                                         \
    const _Float16* _s = Ah + (size_t)(m0 + srow) * K + (t)*64 + (kh)*32 + scol; \
    gload16(_s, A_REGION(buf, kh) + sdst);                                     \
    gload16(_s + (size_t)128 * K, A_REGION(buf, kh) + sdst + 4096);            \
  } while (0)

#define READ_AF(buf, kk, MH)                                                   \
  do {                                                                         \
    _Float16* _b = A_REGION(buf, kk);                                          \
    int _pb = (wr * 64 + (MH)*32 + rp) * 64 + rslot;                           \
    af[0] = *(half8*)&_b[_pb];                                                 \
    af[1] = *(half8*)&_b[_pb + 512];                                           \
    af[2] = *(half8*)&_b[_pb + 1024];                                          \
    af[3] = *(half8*)&_b[_pb + 1536];                                          \
  } while (0)

#define READ_BF(buf, kk)                                                       \
  do {                                                                         \
    _Float16* _b = B_REGION(buf, kk);                                          \
    int _pb = (wc * 32 + rp) * 64 + rslot;                                     \
    bf[0] = *(half8*)&_b[_pb];                                                 \
    bf[1] = *(half8*)&_b[_pb + 512];                                           \
    bf[2] = *(half8*)&_b[_pb + 1024];                                          \
    bf[3] = *(half8*)&_b[_pb + 1536];                                          \
  } while (0)

#define MFMA_Q(MH)                                                             \
  do {                                                                         \
    __builtin_amdgcn_s_setprio(1);                                             \
    _Pragma("unroll") for (int mi = 0; mi < 4; mi++)                           \
        _Pragma("unroll") for (int ni = 0; ni < 4; ni++) acc[(MH)*4 + mi][ni] = \
        MFMA16(af[mi], bf[ni], acc[(MH)*4 + mi][ni]);                          \
    __builtin_amdgcn_s_setprio(0);                                             \
  } while (0)

  STAGE_A16(0, 0, 0);
  STAGE_A16(0, 0, 1);
  STAGE_B(0, 0, 0);
  STAGE_B(0, 0, 1);

  for (int t = 0; t < NT - 1; t++) {
    const int buf = t & 1, nb = buf ^ 1;
    STAGE_A16(t + 1, nb, 0);
    VM(4);
    SCHED0; BARW;
    READ_AF(buf, 0, 0);
    READ_BF(buf, 0);
    LGKM0;
    MFMA_Q(0);
    STAGE_A16(t + 1, nb, 1);
    READ_AF(buf, 0, 1);
    LGKM0;
    MFMA_Q(1);
    STAGE_B(t + 1, nb, 0);
    VM(6);
    SCHED0; BARW;
    READ_AF(buf, 1, 0);
    READ_BF(buf, 1);
    LGKM0;
    MFMA_Q(0);
    STAGE_B(t + 1, nb, 1);
    READ_AF(buf, 1, 1);
    LGKM0;
    MFMA_Q(1);
  }
  {
    VM(2);
    SCHED0; BARW;
    READ_AF(1, 0, 0);
    READ_BF(1, 0);
    LGKM0;
    MFMA_Q(0);
    READ_AF(1, 0, 1);
    LGKM0;
    MFMA_Q(1);
    VM(0);
    SCHED0; BARW;
    READ_AF(1, 1, 0);
    READ_BF(1, 1);
    LGKM0;
    MFMA_Q(0);
    READ_AF(1, 1, 1);
    LGKM0;
    MFMA_Q(1);
  }

#pragma unroll
  for (int ni = 0; ni < 4; ni++) {
    const int col = n0 + wc * 64 + ni * 16 + r15;
    const float bv = bias[col];
#pragma unroll
    for (int mi8 = 0; mi8 < 8; mi8++) {
      const int rowb = m0 + wr * 128 + mi8 * 16 + g * 4;
#pragma unroll
      for (int r = 0; r < 4; r++) {
        float x = (acc[mi8][ni][r] + bv) * scale;
        if (OUT_F32)
          ((float*)Cout)[(size_t)(rowb + r) * NN + col] = x;
        else
          ((_Float16*)Cout)[(size_t)(rowb + r) * NN + col] = (_Float16)x;
      }
    }
  }
#undef A_REGION
#undef B_REGION
#undef STAGE_B
#undef STAGE_A16
#undef READ_AF
#undef READ_BF
#undef MFMA_Q
}

// ---------------- V transpose: Vp(L,B,E) -> Vt[(b*512+c)*64 + d][256 k] ----------------
__global__ __launch_bounds__(256) void vtrans_k(const _Float16* __restrict__ Vp,
                                                _Float16* __restrict__ Vt) {
  const int c = blockIdx.x, b = blockIdx.y;
  __shared__ alignas(16) _Float16 Vl[256 * 64];  // [k][d], chunk ^= k&7
  const int tid = threadIdx.x;
  const int l0 = c * 16;
#pragma unroll
  for (int i = 0; i < 8; i++) {
    int q = tid + i * 256;
    int w = q >> 3, ck = q & 7;
    int ls = l0 + (w >> 4), h = w & 15;
    half8 v = *(const half8*)(Vp + (size_t)(ls * 2 + b) * 1024 + h * 64 + ck * 8);
    *(half8*)&Vl[w * 64 + (ck ^ (w & 7)) * 8] = v;
  }
  __syncthreads();
  const int d = tid >> 2, kcq = tid & 3;
  const size_t obase = ((size_t)(b * 512 + c) * 64 + d) * 256 + kcq * 64;
#pragma unroll
  for (int i8 = 0; i8 < 8; i8++) {
    half8 v;
#pragma unroll
    for (int j = 0; j < 8; j++) {
      int k = kcq * 64 + i8 * 8 + j;
      v[j] = Vl[k * 64 + (((d >> 3) ^ (k & 7)) * 8) + (d & 7)];
    }
    *(half8*)(Vt + obase + i8 * 8) = v;
  }
}

// ---------------- window attention (barrier-free) ----------------
// 256 threads = 4 waves; block covers q-rows [hf*128, hf*128+128) of window c.
// Wave wv = hf*4+wave owns 32 q-rows. S^T = mfma(A=K rows from GLOBAL,
// B=Q rows): lane owns one q-row's scores (k = m*16 + g*4 + reg).
// Softmax: tree max/sum + shfl(16,32); 1/sum deferred to output.
// P (unnormalized) bounced via PRIVATE per-wave LDS slice (16KB total, no
// barriers); PV B-fragments read straight from Vt global (L2-hot).
__global__ __launch_bounds__(256) void attn_win_k(const _Float16* __restrict__ Qp,
                                                  const _Float16* __restrict__ Kp,
                                                  const _Float16* __restrict__ Vt,
                                                  _Float16* __restrict__ Y) {
  const int c = blockIdx.x, b = blockIdx.y, hf = blockIdx.z;
  __shared__ alignas(16) _Float16 Pl[4 * 2048];  // per-wave P slices, no sharing
  const int tid = threadIdx.x, lane = tid & 63, wave = tid >> 6;
  const int i15 = lane & 15, g = lane >> 4;
  const int l0 = c * 16;
  const int wv = hf * 4 + wave;  // virtual wave 0..7 over the window

  // Q fragments (B-operand: lane&15 = q-row)
  half8 qf[2][2];
#pragma unroll
  for (int wf = 0; wf < 2; wf++)
#pragma unroll
    for (int dh = 0; dh < 2; dh++) {
      int ls = l0 + wv * 2 + wf;
      qf[wf][dh] =
          *(const half8*)(Qp + (size_t)(ls * 2 + b) * 1024 + i15 * 64 + dh * 32 + g * 8);
    }

  // S^T accumulate: acc[m][wf], lane holds k = m*16 + g*4 + reg for q-row
  // (wv*32 + wf*16 + i15). K fragments straight from global (L2).
  f32x4 acc[16][2] = {};
#pragma unroll
  for (int m = 0; m < 16; m++) {
    const _Float16* kb = Kp + (size_t)((l0 + m) * 2 + b) * 1024 + i15 * 64 + g * 8;
    half8 a0 = *(const half8*)kb;
    half8 a1 = *(const half8*)(kb + 32);
    __builtin_amdgcn_s_setprio(1);
    acc[m][0] = MFMA16(a0, qf[0][0], acc[m][0]);
    acc[m][0] = MFMA16(a1, qf[0][1], acc[m][0]);
    acc[m][1] = MFMA16(a0, qf[1][0], acc[m][1]);
    acc[m][1] = MFMA16(a1, qf[1][1], acc[m][1]);
    __builtin_amdgcn_s_setprio(0);
  }

  // softmax (scores already in log2 units): tree max, v_exp, tree sum.
  float inv[2];
#pragma unroll
  for (int wf = 0; wf < 2; wf++) {
    f32x4 t[8];
#pragma unroll
    for (int i = 0; i < 8; i++) {
#pragma unroll
      for (int c4 = 0; c4 < 4; c4++)
        t[i][c4] = fmaxf(acc[i][wf][c4], acc[i + 8][wf][c4]);
    }
#pragma unroll
    for (int i = 0; i < 4; i++)
#pragma unroll
      for (int c4 = 0; c4 < 4; c4++) t[i][c4] = fmaxf(t[i][c4], t[i + 4][c4]);
#pragma unroll
    for (int i = 0; i < 2; i++)
#pragma unroll
      for (int c4 = 0; c4 < 4; c4++) t[i][c4] = fmaxf(t[i][c4], t[i + 2][c4]);
#pragma unroll
    for (int c4 = 0; c4 < 4; c4++) t[0][c4] = fmaxf(t[0][c4], t[1][c4]);
    float mx = fmaxf(fmaxf(t[0][0], t[0][1]), fmaxf(t[0][2], t[0][3]));
    mx = fmaxf(mx, __shfl_xor(mx, 16, 64));
    mx = fmaxf(mx, __shfl_xor(mx, 32, 64));
    f32x4 s4 = {0.f, 0.f, 0.f, 0.f};
#pragma unroll
    for (int m = 0; m < 16; m++) {
#pragma unroll
      for (int c4 = 0; c4 < 4; c4++) {
        float e = __builtin_amdgcn_exp2f(acc[m][wf][c4] - mx);
        acc[m][wf][c4] = e;
        s4[c4] += e;
      }
    }
    float sum = (s4[0] + s4[1]) + (s4[2] + s4[3]);
    sum += __shfl_xor(sum, 16, 64);
    sum += __shfl_xor(sum, 32, 64);
    inv[wf] = 1.f / sum;
  }
  // per-output-row inv (output q-row within wave = wf*16 + g*4 + r)
  float invv[2][4];
#pragma unroll
  for (int wf = 0; wf < 2; wf++)
#pragma unroll
    for (int r = 0; r < 4; r++) invv[wf][r] = __shfl(inv[wf], g * 4 + r, 64);

  _Float16* Pw = &Pl[wave * 2048];  // [32 rows][64 k] fp16, chunk ^= row&7
  const size_t vb0 = (size_t)(b * 512 + c) * 64 * 256;
  f32x4 oacc[2][4] = {};
#pragma unroll
  for (int kq = 0; kq < 4; kq++) {
#pragma unroll
    for (int wf = 0; wf < 2; wf++) {
      int rrow = wf * 16 + i15;
#pragma unroll
      for (int ml = 0; ml < 4; ml++) {
        f32x4 pv = acc[kq * 4 + ml][wf];
        half4 h = {(_Float16)pv[0], (_Float16)pv[1], (_Float16)pv[2], (_Float16)pv[3]};
        int ck = ml * 2 + (g >> 1);
        *(half4*)&Pw[rrow * 64 + ((ck ^ (i15 & 7)) * 8) + (g & 1) * 4] = h;
      }
    }
    asm volatile("s_waitcnt lgkmcnt(0)" ::: "memory");
    __builtin_amdgcn_sched_barrier(0);
#pragma unroll
    for (int kfl = 0; kfl < 2; kfl++) {
      half8 pa0 = *(half8*)&Pw[(i15)*64 + (((kfl * 4 + g) ^ (i15 & 7)) * 8)];
      half8 pa1 = *(half8*)&Pw[(16 + i15) * 64 + (((kfl * 4 + g) ^ (i15 & 7)) * 8)];
#pragma unroll
      for (int df = 0; df < 4; df++) {
        // V fragment straight from Vt global (L2-hot, d-major rows)
        half8 vbf = *(const half8*)(Vt + vb0 + (size_t)(df * 16 + i15) * 256 +
                                    (kq * 8 + kfl * 4 + g) * 8);
        __builtin_amdgcn_s_setprio(1);
        oacc[0][df] = MFMA16(pa0, vbf, oacc[0][df]);
        oacc[1][df] = MFMA16(pa1, vbf, oacc[1][df]);
        __builtin_amdgcn_s_setprio(0);
      }
    }
  }

  const int h2 = c >> 5, n = c & 31;
  const size_t yb = ((size_t)(h2 * 2 + b) * 8192 + (size_t)n * 256) * 64;
#pragma unroll
  for (int wf = 0; wf < 2; wf++)
#pragma unroll
    for (int df = 0; df < 4; df++)
#pragma unroll
      for (int r = 0; r < 4; r++) {
        int w = wv * 32 + wf * 16 + g * 4 + r;
        Y[yb + (size_t)w * 64 + df * 16 + i15] =
            (_Float16)(oacc[wf][df][r] * invv[wf][r]);
      }
}

// ---------------- launch ----------------
extern "C" void kernel_launch(void* const* d_in, const int* in_sizes, int n_in,
                              void* d_out, int out_size, void* d_ws, size_t ws_size,
                              hipStream_t stream) {
  const float* query = (const float*)d_in[0];
  const float* key_ = (const float*)d_in[1];
  const float* value = (const float*)d_in[2];
  const float* Wq = (const float*)d_in[3];
  const float* bq = (const float*)d_in[4];
  const float* Wk = (const float*)d_in[5];
  const float* bk = (const float*)d_in[6];
  const float* Wv = (const float*)d_in[7];
  const float* bv = (const float*)d_in[8];
  const float* Wo = (const float*)d_in[9];
  const float* bo = (const float*)d_in[10];

  _Float16* ws = (_Float16*)d_ws;
  _Float16* W16 = ws;                // 4 x 1M halves (8 MB): q,k,v,o
  _Float16* W16q = W16;
  _Float16* W16k = W16 + (1 << 20);
  _Float16* W16v = W16 + 2 * (1 << 20);
  _Float16* W16o = W16 + 3 * (1 << 20);
  _Float16* X16 = ws + 4 * (1 << 20); // 16M halves (32 MB): activations; later Vt
  _Float16* Vp = X16 + (1 << 24);     // 16M halves (32 MB): V proj; later Ybuf
  _Float16* Vt = X16;                 // alias: X16 dead after V proj
  _Float16* Ybuf = Vp;                // alias: Vp dead after vtrans

  _Float16* Qp = (_Float16*)d_out;    // Q,K projections parked in d_out
  _Float16* Kp = Qp + (1 << 24);

  const float qscale = 0.125f * 1.44269504f;  // fold 1/sqrt(D) and log2(e)

  cvtw_k<<<dim3(512, 4), 256, 0, stream>>>(Wq, Wk, Wv, Wo, W16);

  dim3 gg(64, 4), gb(512);

  cvt_fp16_k<<<8192, 256, 0, stream>>>(query, X16, 1 << 24);
  gemm8p_k<0><<<gg, gb, 0, stream>>>(X16, W16q, bq, (void*)Qp, qscale);

  cvt_fp16_k<<<8192, 256, 0, stream>>>(key_, X16, 1 << 24);
  gemm8p_k<0><<<gg, gb, 0, stream>>>(X16, W16k, bk, (void*)Kp, 1.0f);

  cvt_fp16_k<<<8192, 256, 0, stream>>>(value, X16, 1 << 24);
  gemm8p_k<0><<<gg, gb, 0, stream>>>(X16, W16v, bv, (void*)Vp, 1.0f);

  vtrans_k<<<dim3(512, 2), 256, 0, stream>>>(Vp, Vt);
  attn_win_k<<<dim3(512, 2, 2), 256, 0, stream>>>(Qp, Kp, Vt, Ybuf);

  gemm8p_k<1><<<gg, gb, 0, stream>>>(Ybuf, W16o, bo, d_out, 1.0f);

  (void)in_sizes; (void)n_in; (void)out_size; (void)ws_size;
}

// Round 12
// 296.254 us; speedup vs baseline: 1.1708x; 1.1708x over previous
//
#include <hip/hip_runtime.h>

// ---------------------------------------------------------------------------
// EfficientMultiHeadAttention (L=8192,B=2,E=1024,H=16,ws=256,D=64)
// cvt weights -> 3x [cvt activation (roofline) -> fp16 proj GEMM 8-phase] ->
// vtrans -> window attention -> output GEMM (f32 out).
// All GEMMs: 256x256 8-phase counted-vmcnt template (BK=64, K-split halves,
// XOR-swizzled LDS, setprio), A+B via global_load_lds.
// Q projection pre-scaled by 0.125*log2e -> attn softmax uses raw v_exp_f32,
// tree reduces, and defers 1/sum to the output (shfl per q-row).
// Attn: 256-thr blocks (4 waves, z=half-window). K staged in LDS (8x reuse);
// V loaded to REGS at start (T14), written into the dead K region after
// softmax -> LDS 48KB -> 3 blocks/CU. P per-wave 4KB slices.
// ws (72 MB): W16[8] | X16/Vt[32] | Vp/Ybuf[32]; Qp,Kp parked in d_out.
// ---------------------------------------------------------------------------

typedef _Float16 half8 __attribute__((ext_vector_type(8)));
typedef _Float16 half4 __attribute__((ext_vector_type(4)));
typedef float    f32x4 __attribute__((ext_vector_type(4)));

#define MFMA16(a, b, c) __builtin_amdgcn_mfma_f32_16x16x32_f16((a), (b), (c), 0, 0, 0)
#define VM(n) asm volatile("s_waitcnt vmcnt(" #n ")" ::: "memory")
#define SCHED0 __builtin_amdgcn_sched_barrier(0)
#define LGKM0 do { asm volatile("s_waitcnt lgkmcnt(0)" ::: "memory"); SCHED0; } while (0)
#define BARW do { __builtin_amdgcn_s_barrier(); SCHED0; } while (0)

__device__ inline void gload16(const _Float16* g, _Float16* l) {
  __builtin_amdgcn_global_load_lds(
      (const __attribute__((address_space(1))) void*)g,
      (__attribute__((address_space(3))) void*)l, 16, 0, 0);
}

__device__ inline half8 cvt8(float4 a, float4 b) {
  half8 h = {(_Float16)a.x, (_Float16)a.y, (_Float16)a.z, (_Float16)a.w,
             (_Float16)b.x, (_Float16)b.y, (_Float16)b.z, (_Float16)b.w};
  return h;
}

// ---------------- fp32 -> fp16 convert ----------------
__global__ __launch_bounds__(256) void cvt_fp16_k(const float* __restrict__ src,
                                                  _Float16* __restrict__ dst, int n) {
  int i = (blockIdx.x * 256 + threadIdx.x) * 8;
  if (i >= n) return;
  float4 a = *(const float4*)(src + i);
  float4 b = *(const float4*)(src + i + 4);
  *(half8*)(dst + i) = cvt8(a, b);
}

// weights: 4 matrices in one launch
__global__ __launch_bounds__(256) void cvtw_k(const float* __restrict__ s0,
                                              const float* __restrict__ s1,
                                              const float* __restrict__ s2,
                                              const float* __restrict__ s3,
                                              _Float16* __restrict__ d) {
  const float* s = blockIdx.y == 0 ? s0 : blockIdx.y == 1 ? s1 : blockIdx.y == 2 ? s2 : s3;
  _Float16* dst = d + (size_t)blockIdx.y * (1 << 20);
  int i = (blockIdx.x * 256 + threadIdx.x) * 8;
  float4 a = *(const float4*)(s + i);
  float4 b = *(const float4*)(s + i + 4);
  *(half8*)(dst + i) = cvt8(a, b);
}

// ---------------- 256x256 8-phase fp16 GEMM ----------------
// C[m,n] = (sum_k A[m,k]*W[n,k] + bias[n]) * scale; M=16384, N=K=1024, BK=64.
// [round-7 schedule, measured good; do not re-derive]
template <int OUT_F32>
__global__ __launch_bounds__(512) void gemm8p_k(const _Float16* __restrict__ Ah,
                                                const _Float16* __restrict__ Bw,
                                                const float* __restrict__ bias,
                                                void* __restrict__ Cout, float scale) {
  constexpr int K = 1024, NN = 1024, NT = 16;
  __shared__ alignas(16) _Float16 SH[65536];  // A:[0,32768) B:[32768,65536)
  const int tid = threadIdx.x, lane = tid & 63, wave = tid >> 6;
  const int r15 = lane & 15, g = lane >> 4;
  const int wr = wave >> 2, wc = wave & 3;
  const int m0 = blockIdx.x * 256, n0 = blockIdx.y * 256;

  const int sp = tid >> 3;
  const int sv = (tid & 7) ^ (sp & 7);
  const int srow = 2 * sp + (sv >> 2);
  const int scol = (sv & 3) * 8;
  const int sdst = tid * 8;

  const int rp = r15 >> 1, rsub = r15 & 1;
  const int rslot = ((rsub * 4 + g) ^ rp) * 8;

  f32x4 acc[8][4] = {};
  half8 af[4], bf[4];

#define A_REGION(buf, kh) (&SH[(buf)*16384 + (kh)*8192])
#define B_REGION(buf, kh) (&SH[32768 + (buf)*16384 + (kh)*8192])

#define STAGE_B(t, buf, kh)                                                    \
  do {                                                                         \
    const _Float16* _s = Bw + (size_t)(n0 + srow) * K + (t)*64 + (kh)*32 + scol; \
    gload16(_s, B_REGION(buf, kh) + sdst);                                     \
    gload16(_s + (size_t)128 * K, B_REGION(buf, kh) + sdst + 4096);            \
  } while (0)

#define STAGE_A16(t, buf, kh)                                                  \
  do {                                                                         \
    const _Float16* _s = Ah + (size_t)(m0 + srow) * K + (t)*64 + (kh)*32 + scol; \
    gload16(_s, A_REGION(buf, kh) + sdst);                                     \
    gload16(_s + (size_t)128 * K, A_REGION(buf, kh) + sdst + 4096);            \
  } while (0)

#define READ_AF(buf, kk, MH)                                                   \
  do {                                                                         \
    _Float16* _b = A_REGION(buf, kk);                                          \
    int _pb = (wr * 64 + (MH)*32 + rp) * 64 + rslot;                           \
    af[0] = *(half8*)&_b[_pb];                                                 \
    af[1] = *(half8*)&_b[_pb + 512];                                           \
    af[2] = *(half8*)&_b[_pb + 1024];                                          \
    af[3] = *(half8*)&_b[_pb + 1536];                                          \
  } while (0)

#define READ_BF(buf, kk)                                                       \
  do {                                                                         \
    _Float16* _b = B_REGION(buf, kk);                                          \
    int _pb = (wc * 32 + rp) * 64 + rslot;                                     \
    bf[0] = *(half8*)&_b[_pb];                                                 \
    bf[1] = *(half8*)&_b[_pb + 512];                                           \
    bf[2] = *(half8*)&_b[_pb + 1024];                                          \
    bf[3] = *(half8*)&_b[_pb + 1536];                                          \
  } while (0)

#define MFMA_Q(MH)                                                             \
  do {                                                                         \
    __builtin_amdgcn_s_setprio(1);                                             \
    _Pragma("unroll") for (int mi = 0; mi < 4; mi++)                           \
        _Pragma("unroll") for (int ni = 0; ni < 4; ni++) acc[(MH)*4 + mi][ni] = \
        MFMA16(af[mi], bf[ni], acc[(MH)*4 + mi][ni]);                          \
    __builtin_amdgcn_s_setprio(0);                                             \
  } while (0)

  STAGE_A16(0, 0, 0);
  STAGE_A16(0, 0, 1);
  STAGE_B(0, 0, 0);
  STAGE_B(0, 0, 1);

  for (int t = 0; t < NT - 1; t++) {
    const int buf = t & 1, nb = buf ^ 1;
    STAGE_A16(t + 1, nb, 0);
    VM(4);
    SCHED0; BARW;
    READ_AF(buf, 0, 0);
    READ_BF(buf, 0);
    LGKM0;
    MFMA_Q(0);
    STAGE_A16(t + 1, nb, 1);
    READ_AF(buf, 0, 1);
    LGKM0;
    MFMA_Q(1);
    STAGE_B(t + 1, nb, 0);
    VM(6);
    SCHED0; BARW;
    READ_AF(buf, 1, 0);
    READ_BF(buf, 1);
    LGKM0;
    MFMA_Q(0);
    STAGE_B(t + 1, nb, 1);
    READ_AF(buf, 1, 1);
    LGKM0;
    MFMA_Q(1);
  }
  {
    VM(2);
    SCHED0; BARW;
    READ_AF(1, 0, 0);
    READ_BF(1, 0);
    LGKM0;
    MFMA_Q(0);
    READ_AF(1, 0, 1);
    LGKM0;
    MFMA_Q(1);
    VM(0);
    SCHED0; BARW;
    READ_AF(1, 1, 0);
    READ_BF(1, 1);
    LGKM0;
    MFMA_Q(0);
    READ_AF(1, 1, 1);
    LGKM0;
    MFMA_Q(1);
  }

#pragma unroll
  for (int ni = 0; ni < 4; ni++) {
    const int col = n0 + wc * 64 + ni * 16 + r15;
    const float bv = bias[col];
#pragma unroll
    for (int mi8 = 0; mi8 < 8; mi8++) {
      const int rowb = m0 + wr * 128 + mi8 * 16 + g * 4;
#pragma unroll
      for (int r = 0; r < 4; r++) {
        float x = (acc[mi8][ni][r] + bv) * scale;
        if (OUT_F32)
          ((float*)Cout)[(size_t)(rowb + r) * NN + col] = x;
        else
          ((_Float16*)Cout)[(size_t)(rowb + r) * NN + col] = (_Float16)x;
      }
    }
  }
#undef A_REGION
#undef B_REGION
#undef STAGE_B
#undef STAGE_A16
#undef READ_AF
#undef READ_BF
#undef MFMA_Q
}

// ---------------- V transpose: Vp(L,B,E) -> Vt[(b*512+c)*64 + d][256 k] ----------------
__global__ __launch_bounds__(256) void vtrans_k(const _Float16* __restrict__ Vp,
                                                _Float16* __restrict__ Vt) {
  const int c = blockIdx.x, b = blockIdx.y;
  __shared__ alignas(16) _Float16 Vl[256 * 64];  // [k][d], chunk ^= k&7
  const int tid = threadIdx.x;
  const int l0 = c * 16;
#pragma unroll
  for (int i = 0; i < 8; i++) {
    int q = tid + i * 256;
    int w = q >> 3, ck = q & 7;
    int ls = l0 + (w >> 4), h = w & 15;
    half8 v = *(const half8*)(Vp + (size_t)(ls * 2 + b) * 1024 + h * 64 + ck * 8);
    *(half8*)&Vl[w * 64 + (ck ^ (w & 7)) * 8] = v;
  }
  __syncthreads();
  const int d = tid >> 2, kcq = tid & 3;
  const size_t obase = ((size_t)(b * 512 + c) * 64 + d) * 256 + kcq * 64;
#pragma unroll
  for (int i8 = 0; i8 < 8; i8++) {
    half8 v;
#pragma unroll
    for (int j = 0; j < 8; j++) {
      int k = kcq * 64 + i8 * 8 + j;
      v[j] = Vl[k * 64 + (((d >> 3) ^ (k & 7)) * 8) + (d & 7)];
    }
    *(half8*)(Vt + obase + i8 * 8) = v;
  }
}

// ---------------- window attention ----------------
// 256 threads = 4 waves; block covers q-rows [hf*128, hf*128+128) of window c.
// Wave wv = hf*4+wave owns 32 q-rows. S^T = mfma(A=K rows, B=Q rows): lane
// owns one q-row's scores (k = m*16 + g*4 + reg). Q pre-scaled by 0.125*log2e.
// Softmax: tree max/sum + shfl(16,32); 1/sum deferred to output via shfl.
// LDS 48KB: Kl[32K] (K, then V from regs after softmax) + Pl[16K] (per-wave).
__global__ __launch_bounds__(256) void attn_win_k(const _Float16* __restrict__ Qp,
                                                  const _Float16* __restrict__ Kp,
                                                  const _Float16* __restrict__ Vt,
                                                  _Float16* __restrict__ Y) {
  const int c = blockIdx.x, b = blockIdx.y, hf = blockIdx.z;
  __shared__ alignas(16) _Float16 SH[24576];  // 48KB
  _Float16* Kl = SH;            // [k 256][d 64], chunk ^= k&7; later Vl
  _Float16* Vl = SH;            // [d 64][k 256], chunk ^= (d&7)<<2
  _Float16* Pl = SH + 16384;    // 4 waves x 2048 halves
  const int tid = threadIdx.x, lane = tid & 63, wave = tid >> 6;
  const int i15 = lane & 15, g = lane >> 4;
  const int l0 = c * 16;
  const int wv = hf * 4 + wave;  // virtual wave 0..7 over the window

  // V loads -> regs (T14: issue now, write to LDS after softmax)
  const size_t vb0 = (size_t)(b * 512 + c) * 64 * 256;
  half8 vr[8];
#pragma unroll
  for (int i = 0; i < 8; i++) {
    int q = tid + i * 256;
    int d = q >> 5, ck = q & 31;
    vr[i] = *(const half8*)(Vt + vb0 + (size_t)d * 256 + ck * 8);
  }
  // stage K window into LDS
#pragma unroll
  for (int i = 0; i < 8; i++) {
    int q = tid + i * 256;
    int w = q >> 3, ck = q & 7;
    int ls = l0 + (w >> 4), h = w & 15;
    half8 v = *(const half8*)(Kp + (size_t)(ls * 2 + b) * 1024 + h * 64 + ck * 8);
    *(half8*)&Kl[w * 64 + (ck ^ (w & 7)) * 8] = v;
  }
  // Q fragments (B-operand: lane&15 = q-row)
  half8 qf[2][2];
#pragma unroll
  for (int wf = 0; wf < 2; wf++)
#pragma unroll
    for (int dh = 0; dh < 2; dh++) {
      int ls = l0 + wv * 2 + wf;
      qf[wf][dh] =
          *(const half8*)(Qp + (size_t)(ls * 2 + b) * 1024 + i15 * 64 + dh * 32 + g * 8);
    }
  __syncthreads();

  // S^T accumulate: acc[m][wf], lane holds k = m*16 + g*4 + reg for q-row
  // (wv*32 + wf*16 + i15)
  f32x4 acc[16][2] = {};
#pragma unroll
  for (int m = 0; m < 16; m++) {
    int row = m * 16 + i15;
    half8 a0 = *(half8*)&Kl[row * 64 + ((g) ^ (i15 & 7)) * 8];
    half8 a1 = *(half8*)&Kl[row * 64 + ((4 + g) ^ (i15 & 7)) * 8];
    __builtin_amdgcn_s_setprio(1);
    acc[m][0] = MFMA16(a0, qf[0][0], acc[m][0]);
    acc[m][0] = MFMA16(a1, qf[0][1], acc[m][0]);
    acc[m][1] = MFMA16(a0, qf[1][0], acc[m][1]);
    acc[m][1] = MFMA16(a1, qf[1][1], acc[m][1]);
    __builtin_amdgcn_s_setprio(0);
  }

  // softmax (scores already in log2 units): tree max, v_exp, tree sum.
  float inv[2];
#pragma unroll
  for (int wf = 0; wf < 2; wf++) {
    f32x4 t[8];
#pragma unroll
    for (int i = 0; i < 8; i++) {
#pragma unroll
      for (int c4 = 0; c4 < 4; c4++)
        t[i][c4] = fmaxf(acc[i][wf][c4], acc[i + 8][wf][c4]);
    }
#pragma unroll
    for (int i = 0; i < 4; i++)
#pragma unroll
      for (int c4 = 0; c4 < 4; c4++) t[i][c4] = fmaxf(t[i][c4], t[i + 4][c4]);
#pragma unroll
    for (int i = 0; i < 2; i++)
#pragma unroll
      for (int c4 = 0; c4 < 4; c4++) t[i][c4] = fmaxf(t[i][c4], t[i + 2][c4]);
#pragma unroll
    for (int c4 = 0; c4 < 4; c4++) t[0][c4] = fmaxf(t[0][c4], t[1][c4]);
    float mx = fmaxf(fmaxf(t[0][0], t[0][1]), fmaxf(t[0][2], t[0][3]));
    mx = fmaxf(mx, __shfl_xor(mx, 16, 64));
    mx = fmaxf(mx, __shfl_xor(mx, 32, 64));
    f32x4 s4 = {0.f, 0.f, 0.f, 0.f};
#pragma unroll
    for (int m = 0; m < 16; m++) {
#pragma unroll
      for (int c4 = 0; c4 < 4; c4++) {
        float e = __builtin_amdgcn_exp2f(acc[m][wf][c4] - mx);
        acc[m][wf][c4] = e;
        s4[c4] += e;
      }
    }
    float sum = (s4[0] + s4[1]) + (s4[2] + s4[3]);
    sum += __shfl_xor(sum, 16, 64);
    sum += __shfl_xor(sum, 32, 64);
    inv[wf] = 1.f / sum;
  }
  // per-output-row inv (output q-row within wave = wf*16 + g*4 + r)
  float invv[2][4];
#pragma unroll
  for (int wf = 0; wf < 2; wf++)
#pragma unroll
    for (int r = 0; r < 4; r++) invv[wf][r] = __shfl(inv[wf], g * 4 + r, 64);

  __syncthreads();  // all waves done reading Kl
  // write V regs -> Vl (same swizzle as the old staged layout)
#pragma unroll
  for (int i = 0; i < 8; i++) {
    int q = tid + i * 256;
    int d = q >> 5, ck = q & 31;
    *(half8*)&Vl[d * 256 + (ck ^ ((d & 7) << 2)) * 8] = vr[i];
  }
  __syncthreads();  // Vl visible to all waves

  _Float16* Pw = &Pl[wave * 2048];  // [32 rows][64 k] fp16, chunk ^= row&7
  f32x4 oacc[2][4] = {};
#pragma unroll
  for (int kq = 0; kq < 4; kq++) {
#pragma unroll
    for (int wf = 0; wf < 2; wf++) {
      int rrow = wf * 16 + i15;
#pragma unroll
      for (int ml = 0; ml < 4; ml++) {
        f32x4 pv = acc[kq * 4 + ml][wf];
        half4 h = {(_Float16)pv[0], (_Float16)pv[1], (_Float16)pv[2], (_Float16)pv[3]};
        int ck = ml * 2 + (g >> 1);
        *(half4*)&Pw[rrow * 64 + ((ck ^ (i15 & 7)) * 8) + (g & 1) * 4] = h;
      }
    }
    asm volatile("s_waitcnt lgkmcnt(0)" ::: "memory");
    __builtin_amdgcn_sched_barrier(0);
#pragma unroll
    for (int kfl = 0; kfl < 2; kfl++) {
      half8 pa0 = *(half8*)&Pw[(i15)*64 + (((kfl * 4 + g) ^ (i15 & 7)) * 8)];
      half8 pa1 = *(half8*)&Pw[(16 + i15) * 64 + (((kfl * 4 + g) ^ (i15 & 7)) * 8)];
      __builtin_amdgcn_s_setprio(1);
#pragma unroll
      for (int df = 0; df < 4; df++) {
        int drow = df * 16 + i15;
        half8 vbf =
            *(half8*)&Vl[drow * 256 + (((kq * 8 + kfl * 4 + g) ^ ((i15 & 7) << 2)) * 8)];
        oacc[0][df] = MFMA16(pa0, vbf, oacc[0][df]);
        oacc[1][df] = MFMA16(pa1, vbf, oacc[1][df]);
      }
      __builtin_amdgcn_s_setprio(0);
    }
  }

  const int h2 = c >> 5, n = c & 31;
  const size_t yb = ((size_t)(h2 * 2 + b) * 8192 + (size_t)n * 256) * 64;
#pragma unroll
  for (int wf = 0; wf < 2; wf++)
#pragma unroll
    for (int df = 0; df < 4; df++)
#pragma unroll
      for (int r = 0; r < 4; r++) {
        int w = wv * 32 + wf * 16 + g * 4 + r;
        Y[yb + (size_t)w * 64 + df * 16 + i15] =
            (_Float16)(oacc[wf][df][r] * invv[wf][r]);
      }
}

// ---------------- launch ----------------
extern "C" void kernel_launch(void* const* d_in, const int* in_sizes, int n_in,
                              void* d_out, int out_size, void* d_ws, size_t ws_size,
                              hipStream_t stream) {
  const float* query = (const float*)d_in[0];
  const float* key_ = (const float*)d_in[1];
  const float* value = (const float*)d_in[2];
  const float* Wq = (const float*)d_in[3];
  const float* bq = (const float*)d_in[4];
  const float* Wk = (const float*)d_in[5];
  const float* bk = (const float*)d_in[6];
  const float* Wv = (const float*)d_in[7];
  const float* bv = (const float*)d_in[8];
  const float* Wo = (const float*)d_in[9];
  const float* bo = (const float*)d_in[10];

  _Float16* ws = (_Float16*)d_ws;
  _Float16* W16 = ws;                // 4 x 1M halves (8 MB): q,k,v,o
  _Float16* W16q = W16;
  _Float16* W16k = W16 + (1 << 20);
  _Float16* W16v = W16 + 2 * (1 << 20);
  _Float16* W16o = W16 + 3 * (1 << 20);
  _Float16* X16 = ws + 4 * (1 << 20); // 16M halves (32 MB): activations; later Vt
  _Float16* Vp = X16 + (1 << 24);     // 16M halves (32 MB): V proj; later Ybuf
  _Float16* Vt = X16;                 // alias: X16 dead after V proj
  _Float16* Ybuf = Vp;                // alias: Vp dead after vtrans

  _Float16* Qp = (_Float16*)d_out;    // Q,K projections parked in d_out
  _Float16* Kp = Qp + (1 << 24);

  const float qscale = 0.125f * 1.44269504f;  // fold 1/sqrt(D) and log2(e)

  cvtw_k<<<dim3(512, 4), 256, 0, stream>>>(Wq, Wk, Wv, Wo, W16);

  dim3 gg(64, 4), gb(512);

  cvt_fp16_k<<<8192, 256, 0, stream>>>(query, X16, 1 << 24);
  gemm8p_k<0><<<gg, gb, 0, stream>>>(X16, W16q, bq, (void*)Qp, qscale);

  cvt_fp16_k<<<8192, 256, 0, stream>>>(key_, X16, 1 << 24);
  gemm8p_k<0><<<gg, gb, 0, stream>>>(X16, W16k, bk, (void*)Kp, 1.0f);

  cvt_fp16_k<<<8192, 256, 0, stream>>>(value, X16, 1 << 24);
  gemm8p_k<0><<<gg, gb, 0, stream>>>(X16, W16v, bv, (void*)Vp, 1.0f);

  vtrans_k<<<dim3(512, 2), 256, 0, stream>>>(Vp, Vt);
  attn_win_k<<<dim3(512, 2, 2), 256, 0, stream>>>(Qp, Kp, Vt, Ybuf);

  gemm8p_k<1><<<gg, gb, 0, stream>>>(Ybuf, W16o, bo, d_out, 1.0f);

  (void)in_sizes; (void)n_in; (void)out_size; (void)ws_size;
}

// Round 13
// 274.877 us; speedup vs baseline: 1.2618x; 1.0778x over previous
//
#include <hip/hip_runtime.h>

// ---------------------------------------------------------------------------
// EfficientMultiHeadAttention (L=8192,B=2,E=1024,H=16,ws=256,D=64)
// cvt weights -> 3x [cvt activation (roofline) -> fp16 proj GEMM 8-phase] ->
// vtrans -> window attention -> output GEMM (f32 out).
// All GEMMs: 256x256 8-phase counted-vmcnt template (BK=64, K-split halves,
// XOR-swizzled LDS, setprio), A+B via global_load_lds.
// Attn (round-10 structure, measured best): 512 thr / 8 waves / window,
// K+V staged via global_load_lds (linear dest, inverse-swizzled source);
// vmcnt(4) at barrier1 hides V staging under QK^T+softmax (T14);
// P bounced via per-wave slices aliased over dead K region.
// Q projection pre-scaled by 0.125*log2e -> softmax uses raw v_exp_f32,
// tree reduces, 1/sum deferred to output via shfl.
// ws (72 MB): W16[8] | X16/Vt[32] | Vp/Ybuf[32]; Qp,Kp parked in d_out.
// ---------------------------------------------------------------------------

typedef _Float16 half8 __attribute__((ext_vector_type(8)));
typedef _Float16 half4 __attribute__((ext_vector_type(4)));
typedef float    f32x4 __attribute__((ext_vector_type(4)));

#define MFMA16(a, b, c) __builtin_amdgcn_mfma_f32_16x16x32_f16((a), (b), (c), 0, 0, 0)
#define VM(n) asm volatile("s_waitcnt vmcnt(" #n ")" ::: "memory")
#define SCHED0 __builtin_amdgcn_sched_barrier(0)
#define LGKM0 do { asm volatile("s_waitcnt lgkmcnt(0)" ::: "memory"); SCHED0; } while (0)
#define BARW do { __builtin_amdgcn_s_barrier(); SCHED0; } while (0)

__device__ inline void gload16(const _Float16* g, _Float16* l) {
  __builtin_amdgcn_global_load_lds(
      (const __attribute__((address_space(1))) void*)g,
      (__attribute__((address_space(3))) void*)l, 16, 0, 0);
}

__device__ inline half8 cvt8(float4 a, float4 b) {
  half8 h = {(_Float16)a.x, (_Float16)a.y, (_Float16)a.z, (_Float16)a.w,
             (_Float16)b.x, (_Float16)b.y, (_Float16)b.z, (_Float16)b.w};
  return h;
}

// ---------------- fp32 -> fp16 convert ----------------
__global__ __launch_bounds__(256) void cvt_fp16_k(const float* __restrict__ src,
                                                  _Float16* __restrict__ dst, int n) {
  int i = (blockIdx.x * 256 + threadIdx.x) * 8;
  if (i >= n) return;
  float4 a = *(const float4*)(src + i);
  float4 b = *(const float4*)(src + i + 4);
  *(half8*)(dst + i) = cvt8(a, b);
}

// weights: 4 matrices in one launch
__global__ __launch_bounds__(256) void cvtw_k(const float* __restrict__ s0,
                                              const float* __restrict__ s1,
                                              const float* __restrict__ s2,
                                              const float* __restrict__ s3,
                                              _Float16* __restrict__ d) {
  const float* s = blockIdx.y == 0 ? s0 : blockIdx.y == 1 ? s1 : blockIdx.y == 2 ? s2 : s3;
  _Float16* dst = d + (size_t)blockIdx.y * (1 << 20);
  int i = (blockIdx.x * 256 + threadIdx.x) * 8;
  float4 a = *(const float4*)(s + i);
  float4 b = *(const float4*)(s + i + 4);
  *(half8*)(dst + i) = cvt8(a, b);
}

// ---------------- 256x256 8-phase fp16 GEMM ----------------
// C[m,n] = (sum_k A[m,k]*W[n,k] + bias[n]) * scale; M=16384, N=K=1024, BK=64.
// [round-7 schedule, measured good; do not re-derive]
template <int OUT_F32>
__global__ __launch_bounds__(512) void gemm8p_k(const _Float16* __restrict__ Ah,
                                                const _Float16* __restrict__ Bw,
                                                const float* __restrict__ bias,
                                                void* __restrict__ Cout, float scale) {
  constexpr int K = 1024, NN = 1024, NT = 16;
  __shared__ alignas(16) _Float16 SH[65536];  // A:[0,32768) B:[32768,65536)
  const int tid = threadIdx.x, lane = tid & 63, wave = tid >> 6;
  const int r15 = lane & 15, g = lane >> 4;
  const int wr = wave >> 2, wc = wave & 3;
  const int m0 = blockIdx.x * 256, n0 = blockIdx.y * 256;

  const int sp = tid >> 3;
  const int sv = (tid & 7) ^ (sp & 7);
  const int srow = 2 * sp + (sv >> 2);
  const int scol = (sv & 3) * 8;
  const int sdst = tid * 8;

  const int rp = r15 >> 1, rsub = r15 & 1;
  const int rslot = ((rsub * 4 + g) ^ rp) * 8;

  f32x4 acc[8][4] = {};
  half8 af[4], bf[4];

#define A_REGION(buf, kh) (&SH[(buf)*16384 + (kh)*8192])
#define B_REGION(buf, kh) (&SH[32768 + (buf)*16384 + (kh)*8192])

#define STAGE_B(t, buf, kh)                                                    \
  do {                                                                         \
    const _Float16* _s = Bw + (size_t)(n0 + srow) * K + (t)*64 + (kh)*32 + scol; \
    gload16(_s, B_REGION(buf, kh) + sdst);                                     \
    gload16(_s + (size_t)128 * K, B_REGION(buf, kh) + sdst + 4096);            \
  } while (0)

#define STAGE_A16(t, buf, kh)                                                  \
  do {                                                                         \
    const _Float16* _s = Ah + (size_t)(m0 + srow) * K + (t)*64 + (kh)*32 + scol; \
    gload16(_s, A_REGION(buf, kh) + sdst);                                     \
    gload16(_s + (size_t)128 * K, A_REGION(buf, kh) + sdst + 4096);            \
  } while (0)

#define READ_AF(buf, kk, MH)                                                   \
  do {                                                                         \
    _Float16* _b = A_REGION(buf, kk);                                          \
    int _pb = (wr * 64 + (MH)*32 + rp) * 64 + rslot;                           \
    af[0] = *(half8*)&_b[_pb];                                                 \
    af[1] = *(half8*)&_b[_pb + 512];                                           \
    af[2] = *(half8*)&_b[_pb + 1024];                                          \
    af[3] = *(half8*)&_b[_pb + 1536];                                          \
  } while (0)

#define READ_BF(buf, kk)                                                       \
  do {                                                                         \
    _Float16* _b = B_REGION(buf, kk);                                          \
    int _pb = (wc * 32 + rp) * 64 + rslot;                                     \
    bf[0] = *(half8*)&_b[_pb];                                                 \
    bf[1] = *(half8*)&_b[_pb + 512];                                           \
    bf[2] = *(half8*)&_b[_pb + 1024];                                          \
    bf[3] = *(half8*)&_b[_pb + 1536];                                          \
  } while (0)

#define MFMA_Q(MH)                                                             \
  do {                                                                         \
    __builtin_amdgcn_s_setprio(1);                                             \
    _Pragma("unroll") for (int mi = 0; mi < 4; mi++)                           \
        _Pragma("unroll") for (int ni = 0; ni < 4; ni++) acc[(MH)*4 + mi][ni] = \
        MFMA16(af[mi], bf[ni], acc[(MH)*4 + mi][ni]);                          \
    __builtin_amdgcn_s_setprio(0);                                             \
  } while (0)

  STAGE_A16(0, 0, 0);
  STAGE_A16(0, 0, 1);
  STAGE_B(0, 0, 0);
  STAGE_B(0, 0, 1);

  for (int t = 0; t < NT - 1; t++) {
    const int buf = t & 1, nb = buf ^ 1;
    STAGE_A16(t + 1, nb, 0);
    VM(4);
    SCHED0; BARW;
    READ_AF(buf, 0, 0);
    READ_BF(buf, 0);
    LGKM0;
    MFMA_Q(0);
    STAGE_A16(t + 1, nb, 1);
    READ_AF(buf, 0, 1);
    LGKM0;
    MFMA_Q(1);
    STAGE_B(t + 1, nb, 0);
    VM(6);
    SCHED0; BARW;
    READ_AF(buf, 1, 0);
    READ_BF(buf, 1);
    LGKM0;
    MFMA_Q(0);
    STAGE_B(t + 1, nb, 1);
    READ_AF(buf, 1, 1);
    LGKM0;
    MFMA_Q(1);
  }
  {
    VM(2);
    SCHED0; BARW;
    READ_AF(1, 0, 0);
    READ_BF(1, 0);
    LGKM0;
    MFMA_Q(0);
    READ_AF(1, 0, 1);
    LGKM0;
    MFMA_Q(1);
    VM(0);
    SCHED0; BARW;
    READ_AF(1, 1, 0);
    READ_BF(1, 1);
    LGKM0;
    MFMA_Q(0);
    READ_AF(1, 1, 1);
    LGKM0;
    MFMA_Q(1);
  }

#pragma unroll
  for (int ni = 0; ni < 4; ni++) {
    const int col = n0 + wc * 64 + ni * 16 + r15;
    const float bv = bias[col];
#pragma unroll
    for (int mi8 = 0; mi8 < 8; mi8++) {
      const int rowb = m0 + wr * 128 + mi8 * 16 + g * 4;
#pragma unroll
      for (int r = 0; r < 4; r++) {
        float x = (acc[mi8][ni][r] + bv) * scale;
        if (OUT_F32)
          ((float*)Cout)[(size_t)(rowb + r) * NN + col] = x;
        else
          ((_Float16*)Cout)[(size_t)(rowb + r) * NN + col] = (_Float16)x;
      }
    }
  }
#undef A_REGION
#undef B_REGION
#undef STAGE_B
#undef STAGE_A16
#undef READ_AF
#undef READ_BF
#undef MFMA_Q
}

// ---------------- V transpose: Vp(L,B,E) -> Vt[(b*512+c)*64 + d][256 k] ----------------
// staging via global_load_lds (linear dest, inverse-swizzled source)
__global__ __launch_bounds__(256) void vtrans_k(const _Float16* __restrict__ Vp,
                                                _Float16* __restrict__ Vt) {
  const int c = blockIdx.x, b = blockIdx.y;
  __shared__ alignas(16) _Float16 Vl[256 * 64];  // [k][d], chunk ^= k&7
  const int tid = threadIdx.x;
  const int l0 = c * 16;
#pragma unroll
  for (int i = 0; i < 8; i++) {
    int q = tid + i * 256;
    int w = q >> 3, ck = q & 7;
    int ls = l0 + (w >> 4), h = w & 15;
    gload16(Vp + (size_t)(ls * 2 + b) * 1024 + h * 64 + ((ck ^ (w & 7)) * 8),
            &Vl[q * 8]);
  }
  __syncthreads();
  const int d = tid >> 2, kcq = tid & 3;
  const size_t obase = ((size_t)(b * 512 + c) * 64 + d) * 256 + kcq * 64;
#pragma unroll
  for (int i8 = 0; i8 < 8; i8++) {
    half8 v;
#pragma unroll
    for (int j = 0; j < 8; j++) {
      int k = kcq * 64 + i8 * 8 + j;
      v[j] = Vl[k * 64 + (((d >> 3) ^ (k & 7)) * 8) + (d & 7)];
    }
    *(half8*)(Vt + obase + i8 * 8) = v;
  }
}

// ---------------- window attention ----------------
// 512 thr / 8 waves per window (round-10 structure). Wave owns 32 q-rows.
// S^T = mfma(A=K rows, B=Q rows): lane owns one q-row's scores
// (k = m*16 + g*4 + reg). Q pre-scaled by 0.125*log2e.
// K,V staged via global_load_lds; barrier1 waits vmcnt(4) (K+Q only) so V
// staging hides under QK^T+softmax; barrier2 waits vmcnt(0) before PV.
// Softmax: tree max/sum + shfl(16,32); 1/sum deferred to output via shfl.
// P bounced via per-wave 4KB slices aliased over the dead K region.
__global__ __launch_bounds__(512) void attn_win_k(const _Float16* __restrict__ Qp,
                                                  const _Float16* __restrict__ Kp,
                                                  const _Float16* __restrict__ Vt,
                                                  _Float16* __restrict__ Y) {
  const int c = blockIdx.x, b = blockIdx.y;
  __shared__ alignas(16) _Float16 SH[32768];  // 64KB
  _Float16* Kl = SH;            // [k 256][d 64], chunk ^= k&7; later P slices
  _Float16* Vl = SH + 16384;    // [d 64][k 256], chunk ^= (d&7)<<2
  const int tid = threadIdx.x, lane = tid & 63, wave = tid >> 6;
  const int i15 = lane & 15, g = lane >> 4;
  const int l0 = c * 16;
  const size_t vb0 = (size_t)(b * 512 + c) * 64 * 256;

  // --- issue K staging (4 glds): linear dest, inverse-swizzled source
#pragma unroll
  for (int i = 0; i < 4; i++) {
    int q = tid + i * 512;
    int w = q >> 3, ck = q & 7;
    int ls = l0 + (w >> 4), h = w & 15;
    gload16(Kp + (size_t)(ls * 2 + b) * 1024 + h * 64 + ((ck ^ (w & 7)) * 8),
            &Kl[q * 8]);
  }
  SCHED0;
  // --- Q fragments to regs (B-operand: lane&15 = q-row)
  half8 qf[2][2];
#pragma unroll
  for (int wf = 0; wf < 2; wf++)
#pragma unroll
    for (int dh = 0; dh < 2; dh++) {
      int ls = l0 + wave * 2 + wf;
      qf[wf][dh] =
          *(const half8*)(Qp + (size_t)(ls * 2 + b) * 1024 + i15 * 64 + dh * 32 + g * 8);
    }
  SCHED0;
  // --- issue V staging (4 glds) — completes under QK^T+softmax
#pragma unroll
  for (int i = 0; i < 4; i++) {
    int q = tid + i * 512;
    int d = q >> 5, ck = q & 31;
    gload16(Vt + vb0 + (size_t)d * 256 + ((ck ^ ((d & 7) << 2)) * 8), &Vl[q * 8]);
  }
  VM(4);  // K (+Q) done; V's 4 loads still in flight
  SCHED0; BARW;

  // --- S^T accumulate: acc[m][wf], lane holds k = m*16 + g*4 + reg for
  // q-row (wave*32 + wf*16 + i15)
  f32x4 acc[16][2] = {};
#pragma unroll
  for (int m = 0; m < 16; m++) {
    int row = m * 16 + i15;
    half8 a0 = *(half8*)&Kl[row * 64 + ((g) ^ (i15 & 7)) * 8];
    half8 a1 = *(half8*)&Kl[row * 64 + ((4 + g) ^ (i15 & 7)) * 8];
    __builtin_amdgcn_s_setprio(1);
    acc[m][0] = MFMA16(a0, qf[0][0], acc[m][0]);
    acc[m][0] = MFMA16(a1, qf[0][1], acc[m][0]);
    acc[m][1] = MFMA16(a0, qf[1][0], acc[m][1]);
    acc[m][1] = MFMA16(a1, qf[1][1], acc[m][1]);
    __builtin_amdgcn_s_setprio(0);
  }

  // --- softmax (scores in log2 units): tree max, v_exp, tree sum
  float inv[2];
#pragma unroll
  for (int wf = 0; wf < 2; wf++) {
    f32x4 t[8];
#pragma unroll
    for (int i = 0; i < 8; i++) {
#pragma unroll
      for (int c4 = 0; c4 < 4; c4++)
        t[i][c4] = fmaxf(acc[i][wf][c4], acc[i + 8][wf][c4]);
    }
#pragma unroll
    for (int i = 0; i < 4; i++)
#pragma unroll
      for (int c4 = 0; c4 < 4; c4++) t[i][c4] = fmaxf(t[i][c4], t[i + 4][c4]);
#pragma unroll
    for (int i = 0; i < 2; i++)
#pragma unroll
      for (int c4 = 0; c4 < 4; c4++) t[i][c4] = fmaxf(t[i][c4], t[i + 2][c4]);
#pragma unroll
    for (int c4 = 0; c4 < 4; c4++) t[0][c4] = fmaxf(t[0][c4], t[1][c4]);
    float mx = fmaxf(fmaxf(t[0][0], t[0][1]), fmaxf(t[0][2], t[0][3]));
    mx = fmaxf(mx, __shfl_xor(mx, 16, 64));
    mx = fmaxf(mx, __shfl_xor(mx, 32, 64));
    f32x4 s4 = {0.f, 0.f, 0.f, 0.f};
#pragma unroll
    for (int m = 0; m < 16; m++) {
#pragma unroll
      for (int c4 = 0; c4 < 4; c4++) {
        float e = __builtin_amdgcn_exp2f(acc[m][wf][c4] - mx);
        acc[m][wf][c4] = e;
        s4[c4] += e;
      }
    }
    float sum = (s4[0] + s4[1]) + (s4[2] + s4[3]);
    sum += __shfl_xor(sum, 16, 64);
    sum += __shfl_xor(sum, 32, 64);
    inv[wf] = 1.f / sum;
  }
  float invv[2][4];
#pragma unroll
  for (int wf = 0; wf < 2; wf++)
#pragma unroll
    for (int r = 0; r < 4; r++) invv[wf][r] = __shfl(inv[wf], g * 4 + r, 64);

  VM(0);  // V staging fully landed
  SCHED0; BARW;  // all waves done reading Kl -> reuse as per-wave P buffers

  _Float16* Pw = &Kl[wave * 2048];  // [32 rows][64 k] fp16, chunk ^= row&7
  f32x4 oacc[2][4] = {};
#pragma unroll
  for (int kq = 0; kq < 4; kq++) {
#pragma unroll
    for (int wf = 0; wf < 2; wf++) {
      int rrow = wf * 16 + i15;
#pragma unroll
      for (int ml = 0; ml < 4; ml++) {
        f32x4 pv = acc[kq * 4 + ml][wf];
        half4 h = {(_Float16)pv[0], (_Float16)pv[1], (_Float16)pv[2], (_Float16)pv[3]};
        int ck = ml * 2 + (g >> 1);
        *(half4*)&Pw[rrow * 64 + ((ck ^ (i15 & 7)) * 8) + (g & 1) * 4] = h;
      }
    }
    asm volatile("s_waitcnt lgkmcnt(0)" ::: "memory");
    __builtin_amdgcn_sched_barrier(0);
#pragma unroll
    for (int kfl = 0; kfl < 2; kfl++) {
      half8 pa0 = *(half8*)&Pw[(i15)*64 + (((kfl * 4 + g) ^ (i15 & 7)) * 8)];
      half8 pa1 = *(half8*)&Pw[(16 + i15) * 64 + (((kfl * 4 + g) ^ (i15 & 7)) * 8)];
      __builtin_amdgcn_s_setprio(1);
#pragma unroll
      for (int df = 0; df < 4; df++) {
        int drow = df * 16 + i15;
        half8 vbf =
            *(half8*)&Vl[drow * 256 + (((kq * 8 + kfl * 4 + g) ^ ((i15 & 7) << 2)) * 8)];
        oacc[0][df] = MFMA16(pa0, vbf, oacc[0][df]);
        oacc[1][df] = MFMA16(pa1, vbf, oacc[1][df]);
      }
      __builtin_amdgcn_s_setprio(0);
    }
  }

  const int h2 = c >> 5, n = c & 31;
  const size_t yb = ((size_t)(h2 * 2 + b) * 8192 + (size_t)n * 256) * 64;
#pragma unroll
  for (int wf = 0; wf < 2; wf++)
#pragma unroll
    for (int df = 0; df < 4; df++)
#pragma unroll
      for (int r = 0; r < 4; r++) {
        int w = wave * 32 + wf * 16 + g * 4 + r;
        Y[yb + (size_t)w * 64 + df * 16 + i15] =
            (_Float16)(oacc[wf][df][r] * invv[wf][r]);
      }
}

// ---------------- launch ----------------
extern "C" void kernel_launch(void* const* d_in, const int* in_sizes, int n_in,
                              void* d_out, int out_size, void* d_ws, size_t ws_size,
                              hipStream_t stream) {
  const float* query = (const float*)d_in[0];
  const float* key_ = (const float*)d_in[1];
  const float* value = (const float*)d_in[2];
  const float* Wq = (const float*)d_in[3];
  const float* bq = (const float*)d_in[4];
  const float* Wk = (const float*)d_in[5];
  const float* bk = (const float*)d_in[6];
  const float* Wv = (const float*)d_in[7];
  const float* bv = (const float*)d_in[8];
  const float* Wo = (const float*)d_in[9];
  const float* bo = (const float*)d_in[10];

  _Float16* ws = (_Float16*)d_ws;
  _Float16* W16 = ws;                // 4 x 1M halves (8 MB): q,k,v,o
  _Float16* W16q = W16;
  _Float16* W16k = W16 + (1 << 20);
  _Float16* W16v = W16 + 2 * (1 << 20);
  _Float16* W16o = W16 + 3 * (1 << 20);
  _Float16* X16 = ws + 4 * (1 << 20); // 16M halves (32 MB): activations; later Vt
  _Float16* Vp = X16 + (1 << 24);     // 16M halves (32 MB): V proj; later Ybuf
  _Float16* Vt = X16;                 // alias: X16 dead after V proj
  _Float16* Ybuf = Vp;                // alias: Vp dead after vtrans

  _Float16* Qp = (_Float16*)d_out;    // Q,K projections parked in d_out
  _Float16* Kp = Qp + (1 << 24);

  const float qscale = 0.125f * 1.44269504f;  // fold 1/sqrt(D) and log2(e)

  cvtw_k<<<dim3(512, 4), 256, 0, stream>>>(Wq, Wk, Wv, Wo, W16);

  dim3 gg(64, 4), gb(512);

  cvt_fp16_k<<<8192, 256, 0, stream>>>(query, X16, 1 << 24);
  gemm8p_k<0><<<gg, gb, 0, stream>>>(X16, W16q, bq, (void*)Qp, qscale);

  cvt_fp16_k<<<8192, 256, 0, stream>>>(key_, X16, 1 << 24);
  gemm8p_k<0><<<gg, gb, 0, stream>>>(X16, W16k, bk, (void*)Kp, 1.0f);

  cvt_fp16_k<<<8192, 256, 0, stream>>>(value, X16, 1 << 24);
  gemm8p_k<0><<<gg, gb, 0, stream>>>(X16, W16v, bv, (void*)Vp, 1.0f);

  vtrans_k<<<dim3(512, 2), 256, 0, stream>>>(Vp, Vt);
  attn_win_k<<<dim3(512, 2), 512, 0, stream>>>(Qp, Kp, Vt, Ybuf);

  gemm8p_k<1><<<gg, gb, 0, stream>>>(Ybuf, W16o, bo, d_out, 1.0f);

  (void)in_sizes; (void)n_in; (void)out_size; (void)ws_size;
}

// Round 14
// 272.045 us; speedup vs baseline: 1.2750x; 1.0104x over previous
//
#include <hip/hip_runtime.h>

// ---------------------------------------------------------------------------
// EfficientMultiHeadAttention (L=8192,B=2,E=1024,H=16,ws=256,D=64)
// cvt weights -> 3x [cvt activation (roofline) -> fp16 proj GEMM 8-phase] ->
// vtrans -> window attention -> output GEMM (f32 out).
// All GEMMs: 256x256 8-phase counted-vmcnt template (BK=64, K-split halves,
// XOR-swizzled LDS, setprio), A+B via global_load_lds.
// Attn: 512 thr / 8 waves / window; K staged glds (32KB, becomes P region);
// V staged in 4 x 8KB k-chunks, double-buffered (16KB) -> LDS 48KB ->
// 3 blocks/CU; V swizzle chunk^=(d&7) (conflict-free, old <<2 was 4-8 way).
// Q projection pre-scaled by 0.125*log2e -> softmax uses raw v_exp_f32,
// tree reduces, 1/sum deferred to output via shfl.
// ws (72 MB): W16[8] | X16/Vt[32] | Vp/Ybuf[32]; Qp,Kp parked in d_out.
// ---------------------------------------------------------------------------

typedef _Float16 half8 __attribute__((ext_vector_type(8)));
typedef _Float16 half4 __attribute__((ext_vector_type(4)));
typedef float    f32x4 __attribute__((ext_vector_type(4)));

#define MFMA16(a, b, c) __builtin_amdgcn_mfma_f32_16x16x32_f16((a), (b), (c), 0, 0, 0)
#define VM(n) asm volatile("s_waitcnt vmcnt(" #n ")" ::: "memory")
#define SCHED0 __builtin_amdgcn_sched_barrier(0)
#define LGKM0 do { asm volatile("s_waitcnt lgkmcnt(0)" ::: "memory"); SCHED0; } while (0)
#define BARW do { __builtin_amdgcn_s_barrier(); SCHED0; } while (0)

__device__ inline void gload16(const _Float16* g, _Float16* l) {
  __builtin_amdgcn_global_load_lds(
      (const __attribute__((address_space(1))) void*)g,
      (__attribute__((address_space(3))) void*)l, 16, 0, 0);
}

__device__ inline half8 cvt8(float4 a, float4 b) {
  half8 h = {(_Float16)a.x, (_Float16)a.y, (_Float16)a.z, (_Float16)a.w,
             (_Float16)b.x, (_Float16)b.y, (_Float16)b.z, (_Float16)b.w};
  return h;
}

// ---------------- fp32 -> fp16 convert ----------------
__global__ __launch_bounds__(256) void cvt_fp16_k(const float* __restrict__ src,
                                                  _Float16* __restrict__ dst, int n) {
  int i = (blockIdx.x * 256 + threadIdx.x) * 8;
  if (i >= n) return;
  float4 a = *(const float4*)(src + i);
  float4 b = *(const float4*)(src + i + 4);
  *(half8*)(dst + i) = cvt8(a, b);
}

// weights: 4 matrices in one launch
__global__ __launch_bounds__(256) void cvtw_k(const float* __restrict__ s0,
                                              const float* __restrict__ s1,
                                              const float* __restrict__ s2,
                                              const float* __restrict__ s3,
                                              _Float16* __restrict__ d) {
  const float* s = blockIdx.y == 0 ? s0 : blockIdx.y == 1 ? s1 : blockIdx.y == 2 ? s2 : s3;
  _Float16* dst = d + (size_t)blockIdx.y * (1 << 20);
  int i = (blockIdx.x * 256 + threadIdx.x) * 8;
  float4 a = *(const float4*)(s + i);
  float4 b = *(const float4*)(s + i + 4);
  *(half8*)(dst + i) = cvt8(a, b);
}

// ---------------- 256x256 8-phase fp16 GEMM ----------------
// C[m,n] = (sum_k A[m,k]*W[n,k] + bias[n]) * scale; M=16384, N=K=1024, BK=64.
// [round-7 schedule, measured good; do not re-derive]
template <int OUT_F32>
__global__ __launch_bounds__(512) void gemm8p_k(const _Float16* __restrict__ Ah,
                                                const _Float16* __restrict__ Bw,
                                                const float* __restrict__ bias,
                                                void* __restrict__ Cout, float scale) {
  constexpr int K = 1024, NN = 1024, NT = 16;
  __shared__ alignas(16) _Float16 SH[65536];  // A:[0,32768) B:[32768,65536)
  const int tid = threadIdx.x, lane = tid & 63, wave = tid >> 6;
  const int r15 = lane & 15, g = lane >> 4;
  const int wr = wave >> 2, wc = wave & 3;
  const int m0 = blockIdx.x * 256, n0 = blockIdx.y * 256;

  const int sp = tid >> 3;
  const int sv = (tid & 7) ^ (sp & 7);
  const int srow = 2 * sp + (sv >> 2);
  const int scol = (sv & 3) * 8;
  const int sdst = tid * 8;

  const int rp = r15 >> 1, rsub = r15 & 1;
  const int rslot = ((rsub * 4 + g) ^ rp) * 8;

  f32x4 acc[8][4] = {};
  half8 af[4], bf[4];

#define A_REGION(buf, kh) (&SH[(buf)*16384 + (kh)*8192])
#define B_REGION(buf, kh) (&SH[32768 + (buf)*16384 + (kh)*8192])

#define STAGE_B(t, buf, kh)                                                    \
  do {                                                                         \
    const _Float16* _s = Bw + (size_t)(n0 + srow) * K + (t)*64 + (kh)*32 + scol; \
    gload16(_s, B_REGION(buf, kh) + sdst);                                     \
    gload16(_s + (size_t)128 * K, B_REGION(buf, kh) + sdst + 4096);            \
  } while (0)

#define STAGE_A16(t, buf, kh)                                                  \
  do {                                                                         \
    const _Float16* _s = Ah + (size_t)(m0 + srow) * K + (t)*64 + (kh)*32 + scol; \
    gload16(_s, A_REGION(buf, kh) + sdst);                                     \
    gload16(_s + (size_t)128 * K, A_REGION(buf, kh) + sdst + 4096);            \
  } while (0)

#define READ_AF(buf, kk, MH)                                                   \
  do {                                                                         \
    _Float16* _b = A_REGION(buf, kk);                                          \
    int _pb = (wr * 64 + (MH)*32 + rp) * 64 + rslot;                           \
    af[0] = *(half8*)&_b[_pb];                                                 \
    af[1] = *(half8*)&_b[_pb + 512];                                           \
    af[2] = *(half8*)&_b[_pb + 1024];                                          \
    af[3] = *(half8*)&_b[_pb + 1536];                                          \
  } while (0)

#define READ_BF(buf, kk)                                                       \
  do {                                                                         \
    _Float16* _b = B_REGION(buf, kk);                                          \
    int _pb = (wc * 32 + rp) * 64 + rslot;                                     \
    bf[0] = *(half8*)&_b[_pb];                                                 \
    bf[1] = *(half8*)&_b[_pb + 512];                                           \
    bf[2] = *(half8*)&_b[_pb + 1024];                                          \
    bf[3] = *(half8*)&_b[_pb + 1536];                                          \
  } while (0)

#define MFMA_Q(MH)                                                             \
  do {                                                                         \
    __builtin_amdgcn_s_setprio(1);                                             \
    _Pragma("unroll") for (int mi = 0; mi < 4; mi++)                           \
        _Pragma("unroll") for (int ni = 0; ni < 4; ni++) acc[(MH)*4 + mi][ni] = \
        MFMA16(af[mi], bf[ni], acc[(MH)*4 + mi][ni]);                          \
    __builtin_amdgcn_s_setprio(0);                                             \
  } while (0)

  STAGE_A16(0, 0, 0);
  STAGE_A16(0, 0, 1);
  STAGE_B(0, 0, 0);
  STAGE_B(0, 0, 1);

  for (int t = 0; t < NT - 1; t++) {
    const int buf = t & 1, nb = buf ^ 1;
    STAGE_A16(t + 1, nb, 0);
    VM(4);
    SCHED0; BARW;
    READ_AF(buf, 0, 0);
    READ_BF(buf, 0);
    LGKM0;
    MFMA_Q(0);
    STAGE_A16(t + 1, nb, 1);
    READ_AF(buf, 0, 1);
    LGKM0;
    MFMA_Q(1);
    STAGE_B(t + 1, nb, 0);
    VM(6);
    SCHED0; BARW;
    READ_AF(buf, 1, 0);
    READ_BF(buf, 1);
    LGKM0;
    MFMA_Q(0);
    STAGE_B(t + 1, nb, 1);
    READ_AF(buf, 1, 1);
    LGKM0;
    MFMA_Q(1);
  }
  {
    VM(2);
    SCHED0; BARW;
    READ_AF(1, 0, 0);
    READ_BF(1, 0);
    LGKM0;
    MFMA_Q(0);
    READ_AF(1, 0, 1);
    LGKM0;
    MFMA_Q(1);
    VM(0);
    SCHED0; BARW;
    READ_AF(1, 1, 0);
    READ_BF(1, 1);
    LGKM0;
    MFMA_Q(0);
    READ_AF(1, 1, 1);
    LGKM0;
    MFMA_Q(1);
  }

#pragma unroll
  for (int ni = 0; ni < 4; ni++) {
    const int col = n0 + wc * 64 + ni * 16 + r15;
    const float bv = bias[col];
#pragma unroll
    for (int mi8 = 0; mi8 < 8; mi8++) {
      const int rowb = m0 + wr * 128 + mi8 * 16 + g * 4;
#pragma unroll
      for (int r = 0; r < 4; r++) {
        float x = (acc[mi8][ni][r] + bv) * scale;
        if (OUT_F32)
          ((float*)Cout)[(size_t)(rowb + r) * NN + col] = x;
        else
          ((_Float16*)Cout)[(size_t)(rowb + r) * NN + col] = (_Float16)x;
      }
    }
  }
#undef A_REGION
#undef B_REGION
#undef STAGE_B
#undef STAGE_A16
#undef READ_AF
#undef READ_BF
#undef MFMA_Q
}

// ---------------- V transpose: Vp(L,B,E) -> Vt[(b*512+c)*64 + d][256 k] ----------------
// staging via global_load_lds (linear dest, inverse-swizzled source)
__global__ __launch_bounds__(256) void vtrans_k(const _Float16* __restrict__ Vp,
                                                _Float16* __restrict__ Vt) {
  const int c = blockIdx.x, b = blockIdx.y;
  __shared__ alignas(16) _Float16 Vl[256 * 64];  // [k][d], chunk ^= k&7
  const int tid = threadIdx.x;
  const int l0 = c * 16;
#pragma unroll
  for (int i = 0; i < 8; i++) {
    int q = tid + i * 256;
    int w = q >> 3, ck = q & 7;
    int ls = l0 + (w >> 4), h = w & 15;
    gload16(Vp + (size_t)(ls * 2 + b) * 1024 + h * 64 + ((ck ^ (w & 7)) * 8),
            &Vl[q * 8]);
  }
  __syncthreads();
  const int d = tid >> 2, kcq = tid & 3;
  const size_t obase = ((size_t)(b * 512 + c) * 64 + d) * 256 + kcq * 64;
#pragma unroll
  for (int i8 = 0; i8 < 8; i8++) {
    half8 v;
#pragma unroll
    for (int j = 0; j < 8; j++) {
      int k = kcq * 64 + i8 * 8 + j;
      v[j] = Vl[k * 64 + (((d >> 3) ^ (k & 7)) * 8) + (d & 7)];
    }
    *(half8*)(Vt + obase + i8 * 8) = v;
  }
}

// ---------------- window attention ----------------
// 512 thr / 8 waves per window. Wave owns 32 q-rows. S^T = mfma(A=K rows,
// B=Q rows): lane owns one q-row's scores (k = m*16 + g*4 + reg).
// Q pre-scaled by 0.125*log2e. K staged glds into Kl (32KB; P region after
// softmax). V staged in 4 x 8KB k-chunks (double-buffered 16KB); chunk kq+1
// issued post-barrier, flies under PV(kq)+Pwrite(kq+1). Swizzle ^=(d&7)
// (conflict-free; the old <<2 variant was a 4-8 way conflict = 2.1M counter).
// Softmax: tree max/sum + shfl(16,32); 1/sum deferred to output via shfl.
__global__ __launch_bounds__(512) void attn_win_k(const _Float16* __restrict__ Qp,
                                                  const _Float16* __restrict__ Kp,
                                                  const _Float16* __restrict__ Vt,
                                                  _Float16* __restrict__ Y) {
  const int c = blockIdx.x, b = blockIdx.y;
  __shared__ alignas(16) _Float16 SH[24576];  // 48KB
  _Float16* Kl = SH;           // [k 256][d 64], chunk ^= k&7; later P slices
  _Float16* Vb = SH + 16384;   // 2 x [64 d][64 k] chunk buffers, chunk ^= d&7
  const int tid = threadIdx.x, lane = tid & 63, wave = tid >> 6;
  const int i15 = lane & 15, g = lane >> 4;
  const int l0 = c * 16;
  const size_t vb0 = (size_t)(b * 512 + c) * 64 * 256;
  const int vd = tid >> 3, vck = tid & 7;  // V-chunk staging lane mapping

#define STAGE_VCHUNK(kq, buf)                                                  \
  gload16(Vt + vb0 + (size_t)vd * 256 + (kq)*64 + (((vck) ^ (vd & 7)) * 8),    \
          &Vb[(buf)*4096 + tid * 8])

  // --- issue K staging (4 glds): linear dest, inverse-swizzled source
#pragma unroll
  for (int i = 0; i < 4; i++) {
    int q = tid + i * 512;
    int w = q >> 3, ck = q & 7;
    int ls = l0 + (w >> 4), h = w & 15;
    gload16(Kp + (size_t)(ls * 2 + b) * 1024 + h * 64 + ((ck ^ (w & 7)) * 8),
            &Kl[q * 8]);
  }
  SCHED0;
  // --- Q fragments to regs (B-operand: lane&15 = q-row)
  half8 qf[2][2];
#pragma unroll
  for (int wf = 0; wf < 2; wf++)
#pragma unroll
    for (int dh = 0; dh < 2; dh++) {
      int ls = l0 + wave * 2 + wf;
      qf[wf][dh] =
          *(const half8*)(Qp + (size_t)(ls * 2 + b) * 1024 + i15 * 64 + dh * 32 + g * 8);
    }
  SCHED0;
  // --- issue V chunk 0 (completes under QK^T+softmax)
  STAGE_VCHUNK(0, 0);
  VM(1);  // K landed; V chunk 0 still in flight
  SCHED0; BARW;

  // --- S^T accumulate: acc[m][wf], lane holds k = m*16 + g*4 + reg for
  // q-row (wave*32 + wf*16 + i15)
  f32x4 acc[16][2] = {};
#pragma unroll
  for (int m = 0; m < 16; m++) {
    int row = m * 16 + i15;
    half8 a0 = *(half8*)&Kl[row * 64 + ((g) ^ (i15 & 7)) * 8];
    half8 a1 = *(half8*)&Kl[row * 64 + ((4 + g) ^ (i15 & 7)) * 8];
    __builtin_amdgcn_s_setprio(1);
    acc[m][0] = MFMA16(a0, qf[0][0], acc[m][0]);
    acc[m][0] = MFMA16(a1, qf[0][1], acc[m][0]);
    acc[m][1] = MFMA16(a0, qf[1][0], acc[m][1]);
    acc[m][1] = MFMA16(a1, qf[1][1], acc[m][1]);
    __builtin_amdgcn_s_setprio(0);
  }

  // --- softmax (scores in log2 units): tree max, v_exp, tree sum
  float inv[2];
#pragma unroll
  for (int wf = 0; wf < 2; wf++) {
    f32x4 t[8];
#pragma unroll
    for (int i = 0; i < 8; i++) {
#pragma unroll
      for (int c4 = 0; c4 < 4; c4++)
        t[i][c4] = fmaxf(acc[i][wf][c4], acc[i + 8][wf][c4]);
    }
#pragma unroll
    for (int i = 0; i < 4; i++)
#pragma unroll
      for (int c4 = 0; c4 < 4; c4++) t[i][c4] = fmaxf(t[i][c4], t[i + 4][c4]);
#pragma unroll
    for (int i = 0; i < 2; i++)
#pragma unroll
      for (int c4 = 0; c4 < 4; c4++) t[i][c4] = fmaxf(t[i][c4], t[i + 2][c4]);
#pragma unroll
    for (int c4 = 0; c4 < 4; c4++) t[0][c4] = fmaxf(t[0][c4], t[1][c4]);
    float mx = fmaxf(fmaxf(t[0][0], t[0][1]), fmaxf(t[0][2], t[0][3]));
    mx = fmaxf(mx, __shfl_xor(mx, 16, 64));
    mx = fmaxf(mx, __shfl_xor(mx, 32, 64));
    f32x4 s4 = {0.f, 0.f, 0.f, 0.f};
#pragma unroll
    for (int m = 0; m < 16; m++) {
#pragma unroll
      for (int c4 = 0; c4 < 4; c4++) {
        float e = __builtin_amdgcn_exp2f(acc[m][wf][c4] - mx);
        acc[m][wf][c4] = e;
        s4[c4] += e;
      }
    }
    float sum = (s4[0] + s4[1]) + (s4[2] + s4[3]);
    sum += __shfl_xor(sum, 16, 64);
    sum += __shfl_xor(sum, 32, 64);
    inv[wf] = 1.f / sum;
  }
  float invv[2][4];
#pragma unroll
  for (int wf = 0; wf < 2; wf++)
#pragma unroll
    for (int r = 0; r < 4; r++) invv[wf][r] = __shfl(inv[wf], g * 4 + r, 64);

  BARW;  // all waves done reading Kl -> reuse as per-wave P buffers

  _Float16* Pw = &Kl[wave * 2048];  // [32 rows][64 k] fp16, chunk ^= row&7
  f32x4 oacc[2][4] = {};
#pragma unroll
  for (int kq = 0; kq < 4; kq++) {
    // write P slice kq (per-wave private)
#pragma unroll
    for (int wf = 0; wf < 2; wf++) {
      int rrow = wf * 16 + i15;
#pragma unroll
      for (int ml = 0; ml < 4; ml++) {
        f32x4 pv = acc[kq * 4 + ml][wf];
        half4 h = {(_Float16)pv[0], (_Float16)pv[1], (_Float16)pv[2], (_Float16)pv[3]};
        int ck = ml * 2 + (g >> 1);
        *(half4*)&Pw[rrow * 64 + ((ck ^ (i15 & 7)) * 8) + (g & 1) * 4] = h;
      }
    }
    LGKM0;   // P writes visible to self
    VM(0);   // V chunk kq landed (only V in flight)
    SCHED0; BARW;  // block-wide: chunk kq visible; PV(kq-1) buffer free
    if (kq < 3) STAGE_VCHUNK(kq + 1, (kq + 1) & 1);  // flies under PV(kq)
    SCHED0;
    const int vbuf = (kq & 1) * 4096;
#pragma unroll
    for (int kfl = 0; kfl < 2; kfl++) {
      half8 pa0 = *(half8*)&Pw[(i15)*64 + (((kfl * 4 + g) ^ (i15 & 7)) * 8)];
      half8 pa1 = *(half8*)&Pw[(16 + i15) * 64 + (((kfl * 4 + g) ^ (i15 & 7)) * 8)];
      __builtin_amdgcn_s_setprio(1);
#pragma unroll
      for (int df = 0; df < 4; df++) {
        int drow = df * 16 + i15;
        half8 vbf =
            *(half8*)&Vb[vbuf + drow * 64 + (((kfl * 4 + g) ^ (drow & 7)) * 8)];
        oacc[0][df] = MFMA16(pa0, vbf, oacc[0][df]);
        oacc[1][df] = MFMA16(pa1, vbf, oacc[1][df]);
      }
      __builtin_amdgcn_s_setprio(0);
    }
  }

  const int h2 = c >> 5, n = c & 31;
  const size_t yb = ((size_t)(h2 * 2 + b) * 8192 + (size_t)n * 256) * 64;
#pragma unroll
  for (int wf = 0; wf < 2; wf++)
#pragma unroll
    for (int df = 0; df < 4; df++)
#pragma unroll
      for (int r = 0; r < 4; r++) {
        int w = wave * 32 + wf * 16 + g * 4 + r;
        Y[yb + (size_t)w * 64 + df * 16 + i15] =
            (_Float16)(oacc[wf][df][r] * invv[wf][r]);
      }
#undef STAGE_VCHUNK
}

// ---------------- launch ----------------
extern "C" void kernel_launch(void* const* d_in, const int* in_sizes, int n_in,
                              void* d_out, int out_size, void* d_ws, size_t ws_size,
                              hipStream_t stream) {
  const float* query = (const float*)d_in[0];
  const float* key_ = (const float*)d_in[1];
  const float* value = (const float*)d_in[2];
  const float* Wq = (const float*)d_in[3];
  const float* bq = (const float*)d_in[4];
  const float* Wk = (const float*)d_in[5];
  const float* bk = (const float*)d_in[6];
  const float* Wv = (const float*)d_in[7];
  const float* bv = (const float*)d_in[8];
  const float* Wo = (const float*)d_in[9];
  const float* bo = (const float*)d_in[10];

  _Float16* ws = (_Float16*)d_ws;
  _Float16* W16 = ws;                // 4 x 1M halves (8 MB): q,k,v,o
  _Float16* W16q = W16;
  _Float16* W16k = W16 + (1 << 20);
  _Float16* W16v = W16 + 2 * (1 << 20);
  _Float16* W16o = W16 + 3 * (1 << 20);
  _Float16* X16 = ws + 4 * (1 << 20); // 16M halves (32 MB): activations; later Vt
  _Float16* Vp = X16 + (1 << 24);     // 16M halves (32 MB): V proj; later Ybuf
  _Float16* Vt = X16;                 // alias: X16 dead after V proj
  _Float16* Ybuf = Vp;                // alias: Vp dead after vtrans

  _Float16* Qp = (_Float16*)d_out;    // Q,K projections parked in d_out
  _Float16* Kp = Qp + (1 << 24);

  const float qscale = 0.125f * 1.44269504f;  // fold 1/sqrt(D) and log2(e)

  cvtw_k<<<dim3(512, 4), 256, 0, stream>>>(Wq, Wk, Wv, Wo, W16);

  dim3 gg(64, 4), gb(512);

  cvt_fp16_k<<<8192, 256, 0, stream>>>(query, X16, 1 << 24);
  gemm8p_k<0><<<gg, gb, 0, stream>>>(X16, W16q, bq, (void*)Qp, qscale);

  cvt_fp16_k<<<8192, 256, 0, stream>>>(key_, X16, 1 << 24);
  gemm8p_k<0><<<gg, gb, 0, stream>>>(X16, W16k, bk, (void*)Kp, 1.0f);

  cvt_fp16_k<<<8192, 256, 0, stream>>>(value, X16, 1 << 24);
  gemm8p_k<0><<<gg, gb, 0, stream>>>(X16, W16v, bv, (void*)Vp, 1.0f);

  vtrans_k<<<dim3(512, 2), 256, 0, stream>>>(Vp, Vt);
  attn_win_k<<<dim3(512, 2), 512, 0, stream>>>(Qp, Kp, Vt, Ybuf);

  gemm8p_k<1><<<gg, gb, 0, stream>>>(Ybuf, W16o, bo, d_out, 1.0f);

  (void)in_sizes; (void)n_in; (void)out_size; (void)ws_size;
}